// Round 3
// baseline (389.043 us; speedup 1.0000x reference)
//
#include <hip/hip_runtime.h>

#define BATCH 2048
#define NF 512
#define FD 64
#define PAD_B 33                 // 32 rows + 1 pad row
#define CSLOT (16 * PAD_B * 4)   // floats per child slot [kq=16][b=32+1][4] = 2112

// Exact fmaf ordering of the verified kernels (absmax 0.0 preserved).
__device__ __forceinline__ void fma16(float4& acc, const float4 h,
                                      const float4 w0, const float4 w1,
                                      const float4 w2, const float4 w3) {
  acc.x = fmaf(h.x, w0.x, acc.x); acc.y = fmaf(h.x, w0.y, acc.y);
  acc.z = fmaf(h.x, w0.z, acc.z); acc.w = fmaf(h.x, w0.w, acc.w);
  acc.x = fmaf(h.y, w1.x, acc.x); acc.y = fmaf(h.y, w1.y, acc.y);
  acc.z = fmaf(h.y, w1.z, acc.z); acc.w = fmaf(h.y, w1.w, acc.w);
  acc.x = fmaf(h.z, w2.x, acc.x); acc.y = fmaf(h.z, w2.y, acc.y);
  acc.z = fmaf(h.z, w2.z, acc.z); acc.w = fmaf(h.z, w2.w, acc.w);
  acc.x = fmaf(h.w, w3.x, acc.x); acc.y = fmaf(h.w, w3.y, acc.y);
  acc.z = fmaf(h.w, w3.z, acc.z); acc.w = fmaf(h.w, w3.w, acc.w);
}

// ============================================================================
// fused01: block = (L1 node n in [0,32), 32-row tile). 4 waves.
// Stage A: wave (c=w>>1, q=w&1) computes L0 child 2n+c for rows q*16..+16
//          (product from in_graph, matmul W0) -> child LDS slot.
// barrier.
// Stage B: all 4 waves compute L1 node n (8 rows each) -> b1 (workspace).
// One barrier total; every wave busy in every stage.
// ============================================================================
__global__ __launch_bounds__(256) void fused01_kernel(
    const float* __restrict__ in_graph,
    const float* __restrict__ weights,
    const int* __restrict__ fold_idx,
    const int* __restrict__ out_idx,
    float* __restrict__ b1) {
  __shared__ float cslot[2 * CSLOT];   // 16896 B

  const int n    = blockIdx.x >> 6;    // L1 node (grid = 32*64)
  const int tile = blockIdx.x & 63;    // 64 tiles of 32 rows
  const int t  = threadIdx.x;
  const int w  = t >> 6;               // wave 0..3
  const int l  = t & 63;
  const int tx = l & 15;               // j-quad / k-quad lane
  const int ty = l >> 4;               // 0..3

  // fold chain root -> L1 node n (matches layer_kernel's chain bit order)
  int f = out_idx[n >> 2];
  f = fold_idx[(3 * NF + f) * 2 + ((n >> 1) & 1)];
  const int f1 = fold_idx[(2 * NF + f) * 2 + (n & 1)];

  // ---------------- stage A: L0 child c, 16 rows per wave ----------------
  {
    const int c = w >> 1, q = w & 1;
    const int f0 = fold_idx[(1 * NF + f1) * 2 + c];
    const int g0 = fold_idx[f0 * 2 + 0];
    const int g1 = fold_idx[f0 * 2 + 1];
    float* slot = cslot + c * CSLOT + q * 64;   // q*16 rows * 4 floats
    #pragma unroll
    for (int r = 0; r < 4; ++r) {
      const int b = 4 * r + ty;
      const float* row =
          in_graph + (size_t)(tile * 32 + q * 16 + b) * (NF * FD) + tx * 4;
      float4 a  = *(const float4*)(row + g0 * FD);
      float4 c2 = *(const float4*)(row + g1 * FD);
      float4 h;
      h.x = a.x * c2.x; h.y = a.y * c2.y; h.z = a.z * c2.z; h.w = a.w * c2.w;
      *(float4*)(slot + (tx * PAD_B + b) * 4) = h;
    }
    const float* W = weights + (size_t)f0 * (FD * FD);   // layer 0
    float4 acc[4];
    #pragma unroll
    for (int r = 0; r < 4; ++r) acc[r] = make_float4(0.f, 0.f, 0.f, 0.f);
    #pragma unroll 2
    for (int kq = 0; kq < 16; ++kq) {
      const float* Wk = W + kq * 4 * FD + tx * 4;
      float4 w0 = *(const float4*)(Wk);
      float4 w1 = *(const float4*)(Wk + FD);
      float4 w2 = *(const float4*)(Wk + 2 * FD);
      float4 w3 = *(const float4*)(Wk + 3 * FD);
      #pragma unroll
      for (int r = 0; r < 4; ++r) {
        float4 h = *(const float4*)(slot + (kq * PAD_B + 4 * r + ty) * 4);
        fma16(acc[r], h, w0, w1, w2, w3);
      }
    }
    #pragma unroll
    for (int r = 0; r < 4; ++r)
      *(float4*)(slot + (tx * PAD_B + 4 * r + ty) * 4) = acc[r];
  }
  __syncthreads();

  // ---------------- stage B: L1 node n, 8 rows per wave ----------------
  {
    const float* P0 = cslot;
    const float* P1 = cslot + CSLOT;
    const float* W = weights + (size_t)(1 * NF + f1) * (FD * FD);
    float4 acc[2];
    acc[0] = make_float4(0.f, 0.f, 0.f, 0.f);
    acc[1] = make_float4(0.f, 0.f, 0.f, 0.f);
    #pragma unroll 2
    for (int kq = 0; kq < 16; ++kq) {
      const float* Wk = W + kq * 4 * FD + tx * 4;
      float4 w0 = *(const float4*)(Wk);
      float4 w1 = *(const float4*)(Wk + FD);
      float4 w2 = *(const float4*)(Wk + 2 * FD);
      float4 w3 = *(const float4*)(Wk + 3 * FD);
      #pragma unroll
      for (int r = 0; r < 2; ++r) {
        const int b = w * 8 + 4 * r + ty;
        float4 pa = *(const float4*)(P0 + (kq * PAD_B + b) * 4);
        float4 pb = *(const float4*)(P1 + (kq * PAD_B + b) * 4);
        float4 h;
        h.x = pa.x * pb.x; h.y = pa.y * pb.y; h.z = pa.z * pb.z; h.w = pa.w * pb.w;
        fma16(acc[r], h, w0, w1, w2, w3);
      }
    }
    #pragma unroll
    for (int r = 0; r < 2; ++r) {
      const int b = w * 8 + 4 * r + ty;
      *(float4*)(b1 + (size_t)n * (BATCH * FD) +
                 (size_t)(tile * 32 + b) * FD + tx * 4) = acc[r];
    }
  }
}

// ============================================================================
// fused23: block = (output o in [0,8), 32-row tile). Same 2-stage shape:
// Stage A: L2 node m = 2o+c from b1 pairs -> child LDS slot.
// Stage B: L3 node o -> out[b][o][:].
// ============================================================================
__global__ __launch_bounds__(256) void fused23_kernel(
    const float* __restrict__ b1,
    const float* __restrict__ weights,
    const int* __restrict__ fold_idx,
    const int* __restrict__ out_idx,
    float* __restrict__ out) {
  __shared__ float cslot[2 * CSLOT];

  const int o    = blockIdx.x >> 6;    // output (grid = 8*64)
  const int tile = blockIdx.x & 63;
  const int t  = threadIdx.x;
  const int w  = t >> 6;
  const int l  = t & 63;
  const int tx = l & 15;
  const int ty = l >> 4;

  const int froot = out_idx[o];
  const long NB = (long)BATCH * FD;

  // ---------------- stage A: L2 node m = 2o + c ----------------
  {
    const int c = w >> 1, q = w & 1;
    const int m  = 2 * o + c;
    const int f2 = fold_idx[(3 * NF + froot) * 2 + c];
    float* slot = cslot + c * CSLOT + q * 64;
    const float* p0 = b1 + (size_t)(2 * m) * NB + tx * 4;
    const float* p1 = b1 + (size_t)(2 * m + 1) * NB + tx * 4;
    #pragma unroll
    for (int r = 0; r < 4; ++r) {
      const int b = 4 * r + ty;
      const size_t roff = (size_t)(tile * 32 + q * 16 + b) * FD;
      float4 a  = *(const float4*)(p0 + roff);
      float4 c2 = *(const float4*)(p1 + roff);
      float4 h;
      h.x = a.x * c2.x; h.y = a.y * c2.y; h.z = a.z * c2.z; h.w = a.w * c2.w;
      *(float4*)(slot + (tx * PAD_B + b) * 4) = h;
    }
    const float* W = weights + (size_t)(2 * NF + f2) * (FD * FD);
    float4 acc[4];
    #pragma unroll
    for (int r = 0; r < 4; ++r) acc[r] = make_float4(0.f, 0.f, 0.f, 0.f);
    #pragma unroll 2
    for (int kq = 0; kq < 16; ++kq) {
      const float* Wk = W + kq * 4 * FD + tx * 4;
      float4 w0 = *(const float4*)(Wk);
      float4 w1 = *(const float4*)(Wk + FD);
      float4 w2 = *(const float4*)(Wk + 2 * FD);
      float4 w3 = *(const float4*)(Wk + 3 * FD);
      #pragma unroll
      for (int r = 0; r < 4; ++r) {
        float4 h = *(const float4*)(slot + (kq * PAD_B + 4 * r + ty) * 4);
        fma16(acc[r], h, w0, w1, w2, w3);
      }
    }
    #pragma unroll
    for (int r = 0; r < 4; ++r)
      *(float4*)(slot + (tx * PAD_B + 4 * r + ty) * 4) = acc[r];
  }
  __syncthreads();

  // ---------------- stage B: L3 node o -> out ----------------
  {
    const float* P0 = cslot;
    const float* P1 = cslot + CSLOT;
    const float* W = weights + (size_t)(3 * NF + froot) * (FD * FD);
    float4 acc[2];
    acc[0] = make_float4(0.f, 0.f, 0.f, 0.f);
    acc[1] = make_float4(0.f, 0.f, 0.f, 0.f);
    #pragma unroll 2
    for (int kq = 0; kq < 16; ++kq) {
      const float* Wk = W + kq * 4 * FD + tx * 4;
      float4 w0 = *(const float4*)(Wk);
      float4 w1 = *(const float4*)(Wk + FD);
      float4 w2 = *(const float4*)(Wk + 2 * FD);
      float4 w3 = *(const float4*)(Wk + 3 * FD);
      #pragma unroll
      for (int r = 0; r < 2; ++r) {
        const int b = w * 8 + 4 * r + ty;
        float4 pa = *(const float4*)(P0 + (kq * PAD_B + b) * 4);
        float4 pb = *(const float4*)(P1 + (kq * PAD_B + b) * 4);
        float4 h;
        h.x = pa.x * pb.x; h.y = pa.y * pb.y; h.z = pa.z * pb.z; h.w = pa.w * pb.w;
        fma16(acc[r], h, w0, w1, w2, w3);
      }
    }
    #pragma unroll
    for (int r = 0; r < 2; ++r) {
      const int b = w * 8 + 4 * r + ty;
      *(float4*)(out + (size_t)(tile * 32 + b) * (8 * FD) + o * FD + tx * 4) = acc[r];
    }
  }
}

// ============================================================================
// Fallback: proven fused in-block tree kernel (used only if ws too small).
// ============================================================================
#define BT 16
#define SLOTF (16 * 17 * 4)
__global__ __launch_bounds__(512) void fused_dag_kernel(
    const float* __restrict__ in_graph,
    const float* __restrict__ weights,
    const int* __restrict__ fold_idx,
    const int* __restrict__ out_idx,
    float* __restrict__ out) {
  __shared__ float bufA[8 * SLOTF];
  __shared__ float bufB[4 * SLOTF];
  __shared__ int T[32];

  const int o    = blockIdx.x & 7;
  const int tile = blockIdx.x >> 3;
  const int B0   = tile * BT;
  const int t    = threadIdx.x;

  if (t == 0) {
    int f4 = out_idx[o];
    T[0] = f4;
    T[1] = fold_idx[(3 * NF + f4) * 2 + 0];
    T[2] = fold_idx[(3 * NF + f4) * 2 + 1];
    #pragma unroll
    for (int i = 0; i < 2; ++i) {
      int f = T[1 + i];
      T[3 + 2 * i]     = fold_idx[(2 * NF + f) * 2 + 0];
      T[3 + 2 * i + 1] = fold_idx[(2 * NF + f) * 2 + 1];
    }
    #pragma unroll
    for (int i = 0; i < 4; ++i) {
      int f = T[3 + i];
      T[7 + 2 * i]     = fold_idx[(1 * NF + f) * 2 + 0];
      T[7 + 2 * i + 1] = fold_idx[(1 * NF + f) * 2 + 1];
    }
    #pragma unroll
    for (int i = 0; i < 8; ++i) {
      int f = T[7 + i];
      T[15 + 2 * i]     = fold_idx[(0 * NF + f) * 2 + 0];
      T[15 + 2 * i + 1] = fold_idx[(0 * NF + f) * 2 + 1];
    }
  }
  __syncthreads();

  const int w  = t >> 6;
  const int l  = t & 63;
  const int tx = l & 15;
  const int ty = l >> 4;

  {
    const int node = w;
    float* slot = bufA + node * SLOTF;
    const int f0 = T[15 + 2 * node];
    const int f1 = T[16 + 2 * node];
    #pragma unroll
    for (int r = 0; r < 4; ++r) {
      const int b = ty * 4 + r;
      const float* row = in_graph + (size_t)(B0 + b) * NF * FD + tx * 4;
      float4 a = *(const float4*)(row + f0 * FD);
      float4 c = *(const float4*)(row + f1 * FD);
      float4 h;
      h.x = a.x * c.x; h.y = a.y * c.y; h.z = a.z * c.z; h.w = a.w * c.w;
      *(float4*)(slot + (tx * 17 + b) * 4) = h;
    }
    const float* W = weights + (size_t)(0 * NF + T[7 + node]) * (FD * FD);
    float4 acc[4];
    #pragma unroll
    for (int r = 0; r < 4; ++r) acc[r] = make_float4(0.f, 0.f, 0.f, 0.f);
    #pragma unroll 2
    for (int kq = 0; kq < 16; ++kq) {
      const float* Wk = W + kq * 4 * FD + tx * 4;
      float4 w0 = *(const float4*)(Wk);
      float4 w1 = *(const float4*)(Wk + FD);
      float4 w2 = *(const float4*)(Wk + 2 * FD);
      float4 w3 = *(const float4*)(Wk + 3 * FD);
      #pragma unroll
      for (int r = 0; r < 4; ++r) {
        float4 h = *(const float4*)(slot + (kq * 17 + 4 * r + ty) * 4);
        fma16(acc[r], h, w0, w1, w2, w3);
      }
    }
    #pragma unroll
    for (int r = 0; r < 4; ++r)
      *(float4*)(slot + (tx * 17 + 4 * r + ty) * 4) = acc[r];
  }
  __syncthreads();

  {
    const int node = w >> 1, half = w & 1;
    const float* P0 = bufA + (2 * node) * SLOTF;
    const float* P1 = bufA + (2 * node + 1) * SLOTF;
    const float* W = weights + (size_t)(1 * NF + T[3 + node]) * (FD * FD);
    float* slot = bufB + node * SLOTF;
    float4 acc[2];
    acc[0] = make_float4(0.f, 0.f, 0.f, 0.f);
    acc[1] = make_float4(0.f, 0.f, 0.f, 0.f);
    #pragma unroll 2
    for (int kq = 0; kq < 16; ++kq) {
      const float* Wk = W + kq * 4 * FD + tx * 4;
      float4 w0 = *(const float4*)(Wk);
      float4 w1 = *(const float4*)(Wk + FD);
      float4 w2 = *(const float4*)(Wk + 2 * FD);
      float4 w3 = *(const float4*)(Wk + 3 * FD);
      #pragma unroll
      for (int r = 0; r < 2; ++r) {
        const int b = half * 8 + 4 * r + ty;
        float4 pa = *(const float4*)(P0 + (kq * 17 + b) * 4);
        float4 pb = *(const float4*)(P1 + (kq * 17 + b) * 4);
        float4 h;
        h.x = pa.x * pb.x; h.y = pa.y * pb.y; h.z = pa.z * pb.z; h.w = pa.w * pb.w;
        fma16(acc[r], h, w0, w1, w2, w3);
      }
    }
    #pragma unroll
    for (int r = 0; r < 2; ++r)
      *(float4*)(slot + (tx * 17 + half * 8 + 4 * r + ty) * 4) = acc[r];
  }
  __syncthreads();

  {
    const int node = w >> 2, q = w & 3;
    const float* P0 = bufB + (2 * node) * SLOTF;
    const float* P1 = bufB + (2 * node + 1) * SLOTF;
    const float* W = weights + (size_t)(2 * NF + T[1 + node]) * (FD * FD);
    float* slot = bufA + node * SLOTF;
    const int b = q * 4 + ty;
    float4 acc = make_float4(0.f, 0.f, 0.f, 0.f);
    #pragma unroll 2
    for (int kq = 0; kq < 16; ++kq) {
      const float* Wk = W + kq * 4 * FD + tx * 4;
      float4 w0 = *(const float4*)(Wk);
      float4 w1 = *(const float4*)(Wk + FD);
      float4 w2 = *(const float4*)(Wk + 2 * FD);
      float4 w3 = *(const float4*)(Wk + 3 * FD);
      float4 pa = *(const float4*)(P0 + (kq * 17 + b) * 4);
      float4 pb = *(const float4*)(P1 + (kq * 17 + b) * 4);
      float4 h;
      h.x = pa.x * pb.x; h.y = pa.y * pb.y; h.z = pa.z * pb.z; h.w = pa.w * pb.w;
      fma16(acc, h, w0, w1, w2, w3);
    }
    *(float4*)(slot + (tx * 17 + b) * 4) = acc;
  }
  __syncthreads();

  if (w < 4) {
    const float* P0 = bufA + 0 * SLOTF;
    const float* P1 = bufA + 1 * SLOTF;
    const float* W = weights + (size_t)(3 * NF + T[0]) * (FD * FD);
    const int b = w * 4 + ty;
    float4 acc = make_float4(0.f, 0.f, 0.f, 0.f);
    #pragma unroll 2
    for (int kq = 0; kq < 16; ++kq) {
      const float* Wk = W + kq * 4 * FD + tx * 4;
      float4 w0 = *(const float4*)(Wk);
      float4 w1 = *(const float4*)(Wk + FD);
      float4 w2 = *(const float4*)(Wk + 2 * FD);
      float4 w3 = *(const float4*)(Wk + 3 * FD);
      float4 pa = *(const float4*)(P0 + (kq * 17 + b) * 4);
      float4 pb = *(const float4*)(P1 + (kq * 17 + b) * 4);
      float4 h;
      h.x = pa.x * pb.x; h.y = pa.y * pb.y; h.z = pa.z * pb.z; h.w = pa.w * pb.w;
      fma16(acc, h, w0, w1, w2, w3);
    }
    *(float4*)(out + ((size_t)(B0 + b) * 8 + o) * FD + tx * 4) = acc;
  }
}

extern "C" void kernel_launch(void* const* d_in, const int* in_sizes, int n_in,
                              void* d_out, int out_size, void* d_ws, size_t ws_size,
                              hipStream_t stream) {
  const float* in_graph = (const float*)d_in[0];
  const float* weights  = (const float*)d_in[1];
  const int*   fold_idx = (const int*)d_in[2];
  const int*   out_idx  = (const int*)d_in[3];
  float* out = (float*)d_out;

  const size_t need = 32ull * BATCH * FD * sizeof(float);   // 16.8 MB for b1

  if (ws_size >= need) {
    float* b1 = (float*)d_ws;
    // L0+L1 fused: 32 L1-nodes x 64 tiles of 32 rows
    fused01_kernel<<<32 * 64, 256, 0, stream>>>(
        in_graph, weights, fold_idx, out_idx, b1);
    // L2+L3 fused: 8 outputs x 64 tiles of 32 rows
    fused23_kernel<<<8 * 64, 256, 0, stream>>>(
        b1, weights, fold_idx, out_idx, out);
  } else {
    fused_dag_kernel<<<(BATCH / BT) * 8, 512, 0, stream>>>(
        in_graph, weights, fold_idx, out_idx, out);
  }
}

// Round 4
// 377.100 us; speedup vs baseline: 1.0317x; 1.0317x over previous
//
#include <hip/hip_runtime.h>

#define BATCH 2048
#define NF 512
#define FD 64
#define BT 16                 // batch rows per block
#define SLOTF (16 * 17 * 4)   // floats per LDS slot: [kq=16][b=16+1pad][4]

// One block = (output o, batch tile of 16 rows). Entire 15-node subtree
// computed in-block; intermediates live in LDS only (zero HBM round-trip).
// Slot layout [kq][b][c] holds value[b][4*kq+c]; child k = parent j, so the
// same layout serves C-stores (j-indexed) and H-reads (k-indexed).
// Compute rows b = 4r+ty -> k-loop ds_read_b128 are conflict-free
// (4 banks x 16-lane broadcast). Staging/C-stores are 8-way but once/node.
// Best-measured variant (376.0 us, absmax 0.0). dur_us is dominated by
// ~330 us of harness re-poison fills; device time of this kernel is <159 us.
__global__ __launch_bounds__(512) void fused_dag_kernel(
    const float* __restrict__ in_graph,
    const float* __restrict__ weights,
    const int* __restrict__ fold_idx,
    const int* __restrict__ out_idx,
    float* __restrict__ out) {
  __shared__ float bufA[8 * SLOTF];   // L1 outs; reused for L3 outs
  __shared__ float bufB[4 * SLOTF];   // L2 outs
  __shared__ int T[32];  // 0:F4 | 1..2:F3 | 3..6:F2 | 7..14:F1 | 15..30:F0

  const int o    = blockIdx.x & 7;
  const int tile = blockIdx.x >> 3;
  const int B0   = tile * BT;
  const int t    = threadIdx.x;

  // ---- per-block fold-table rebuild (5 dependent levels, L2-hot) ----
  if (t == 0) {
    int f4 = out_idx[o];
    T[0] = f4;
    T[1] = fold_idx[(3 * NF + f4) * 2 + 0];
    T[2] = fold_idx[(3 * NF + f4) * 2 + 1];
    #pragma unroll
    for (int i = 0; i < 2; ++i) {
      int f = T[1 + i];
      T[3 + 2 * i]     = fold_idx[(2 * NF + f) * 2 + 0];
      T[3 + 2 * i + 1] = fold_idx[(2 * NF + f) * 2 + 1];
    }
    #pragma unroll
    for (int i = 0; i < 4; ++i) {
      int f = T[3 + i];
      T[7 + 2 * i]     = fold_idx[(1 * NF + f) * 2 + 0];
      T[7 + 2 * i + 1] = fold_idx[(1 * NF + f) * 2 + 1];
    }
    #pragma unroll
    for (int i = 0; i < 8; ++i) {
      int f = T[7 + i];
      T[15 + 2 * i]     = fold_idx[(0 * NF + f) * 2 + 0];
      T[15 + 2 * i + 1] = fold_idx[(0 * NF + f) * 2 + 1];
    }
  }
  __syncthreads();

  const int w  = t >> 6;    // wave 0..7
  const int l  = t & 63;
  const int tx = l & 15;    // j-quad (cols 4*tx..+3)
  const int ty = l >> 4;    // 0..3

  // ================= stage 1: 8 nodes, 1 wave each =================
  {
    const int node = w;
    float* slot = bufA + node * SLOTF;
    const int f0 = T[15 + 2 * node];
    const int f1 = T[16 + 2 * node];
    // H = x[f0] (.) x[f1] staged into own output slot (k-fast lanes = coalesced)
    #pragma unroll
    for (int r = 0; r < 4; ++r) {
      const int b = ty * 4 + r;
      const float* row = in_graph + (size_t)(B0 + b) * NF * FD + tx * 4;
      float4 a = *(const float4*)(row + f0 * FD);
      float4 c = *(const float4*)(row + f1 * FD);
      float4 h;
      h.x = a.x * c.x; h.y = a.y * c.y; h.z = a.z * c.z; h.w = a.w * c.w;
      *(float4*)(slot + (tx * 17 + b) * 4) = h;
    }
    const float* W = weights + (size_t)(0 * NF + T[7 + node]) * (FD * FD);
    float4 acc[4];
    #pragma unroll
    for (int r = 0; r < 4; ++r) acc[r] = make_float4(0.f, 0.f, 0.f, 0.f);
    #pragma unroll 2
    for (int kq = 0; kq < 16; ++kq) {
      const float* Wk = W + kq * 4 * FD + tx * 4;
      float4 w0 = *(const float4*)(Wk);
      float4 w1 = *(const float4*)(Wk + FD);
      float4 w2 = *(const float4*)(Wk + 2 * FD);
      float4 w3 = *(const float4*)(Wk + 3 * FD);
      #pragma unroll
      for (int r = 0; r < 4; ++r) {
        float4 h = *(const float4*)(slot + (kq * 17 + 4 * r + ty) * 4);
        acc[r].x = fmaf(h.x, w0.x, acc[r].x); acc[r].y = fmaf(h.x, w0.y, acc[r].y);
        acc[r].z = fmaf(h.x, w0.z, acc[r].z); acc[r].w = fmaf(h.x, w0.w, acc[r].w);
        acc[r].x = fmaf(h.y, w1.x, acc[r].x); acc[r].y = fmaf(h.y, w1.y, acc[r].y);
        acc[r].z = fmaf(h.y, w1.z, acc[r].z); acc[r].w = fmaf(h.y, w1.w, acc[r].w);
        acc[r].x = fmaf(h.z, w2.x, acc[r].x); acc[r].y = fmaf(h.z, w2.y, acc[r].y);
        acc[r].z = fmaf(h.z, w2.z, acc[r].z); acc[r].w = fmaf(h.z, w2.w, acc[r].w);
        acc[r].x = fmaf(h.w, w3.x, acc[r].x); acc[r].y = fmaf(h.w, w3.y, acc[r].y);
        acc[r].z = fmaf(h.w, w3.z, acc[r].z); acc[r].w = fmaf(h.w, w3.w, acc[r].w);
      }
    }
    #pragma unroll
    for (int r = 0; r < 4; ++r)
      *(float4*)(slot + (tx * 17 + 4 * r + ty) * 4) = acc[r];
  }
  __syncthreads();

  // ================= stage 2: 4 nodes, 2 waves each =================
  {
    const int node = w >> 1, half = w & 1;
    const float* P0 = bufA + (2 * node) * SLOTF;
    const float* P1 = bufA + (2 * node + 1) * SLOTF;
    const float* W = weights + (size_t)(1 * NF + T[3 + node]) * (FD * FD);
    float* slot = bufB + node * SLOTF;
    float4 acc[2];
    acc[0] = make_float4(0.f, 0.f, 0.f, 0.f);
    acc[1] = make_float4(0.f, 0.f, 0.f, 0.f);
    #pragma unroll 2
    for (int kq = 0; kq < 16; ++kq) {
      const float* Wk = W + kq * 4 * FD + tx * 4;
      float4 w0 = *(const float4*)(Wk);
      float4 w1 = *(const float4*)(Wk + FD);
      float4 w2 = *(const float4*)(Wk + 2 * FD);
      float4 w3 = *(const float4*)(Wk + 3 * FD);
      #pragma unroll
      for (int r = 0; r < 2; ++r) {
        const int b = half * 8 + 4 * r + ty;
        float4 pa = *(const float4*)(P0 + (kq * 17 + b) * 4);
        float4 pb = *(const float4*)(P1 + (kq * 17 + b) * 4);
        float4 h;
        h.x = pa.x * pb.x; h.y = pa.y * pb.y; h.z = pa.z * pb.z; h.w = pa.w * pb.w;
        acc[r].x = fmaf(h.x, w0.x, acc[r].x); acc[r].y = fmaf(h.x, w0.y, acc[r].y);
        acc[r].z = fmaf(h.x, w0.z, acc[r].z); acc[r].w = fmaf(h.x, w0.w, acc[r].w);
        acc[r].x = fmaf(h.y, w1.x, acc[r].x); acc[r].y = fmaf(h.y, w1.y, acc[r].y);
        acc[r].z = fmaf(h.y, w1.z, acc[r].z); acc[r].w = fmaf(h.y, w1.w, acc[r].w);
        acc[r].x = fmaf(h.z, w2.x, acc[r].x); acc[r].y = fmaf(h.z, w2.y, acc[r].y);
        acc[r].z = fmaf(h.z, w2.z, acc[r].z); acc[r].w = fmaf(h.z, w2.w, acc[r].w);
        acc[r].x = fmaf(h.w, w3.x, acc[r].x); acc[r].y = fmaf(h.w, w3.y, acc[r].y);
        acc[r].z = fmaf(h.w, w3.z, acc[r].z); acc[r].w = fmaf(h.w, w3.w, acc[r].w);
      }
    }
    #pragma unroll
    for (int r = 0; r < 2; ++r)
      *(float4*)(slot + (tx * 17 + half * 8 + 4 * r + ty) * 4) = acc[r];
  }
  __syncthreads();

  // ================= stage 3: 2 nodes, 4 waves each =================
  {
    const int node = w >> 2, q = w & 3;
    const float* P0 = bufB + (2 * node) * SLOTF;
    const float* P1 = bufB + (2 * node + 1) * SLOTF;
    const float* W = weights + (size_t)(2 * NF + T[1 + node]) * (FD * FD);
    float* slot = bufA + node * SLOTF;   // bufA dead after stage 2
    const int b = q * 4 + ty;
    float4 acc = make_float4(0.f, 0.f, 0.f, 0.f);
    #pragma unroll 2
    for (int kq = 0; kq < 16; ++kq) {
      const float* Wk = W + kq * 4 * FD + tx * 4;
      float4 w0 = *(const float4*)(Wk);
      float4 w1 = *(const float4*)(Wk + FD);
      float4 w2 = *(const float4*)(Wk + 2 * FD);
      float4 w3 = *(const float4*)(Wk + 3 * FD);
      float4 pa = *(const float4*)(P0 + (kq * 17 + b) * 4);
      float4 pb = *(const float4*)(P1 + (kq * 17 + b) * 4);
      float4 h;
      h.x = pa.x * pb.x; h.y = pa.y * pb.y; h.z = pa.z * pb.z; h.w = pa.w * pb.w;
      acc.x = fmaf(h.x, w0.x, acc.x); acc.y = fmaf(h.x, w0.y, acc.y);
      acc.z = fmaf(h.x, w0.z, acc.z); acc.w = fmaf(h.x, w0.w, acc.w);
      acc.x = fmaf(h.y, w1.x, acc.x); acc.y = fmaf(h.y, w1.y, acc.y);
      acc.z = fmaf(h.y, w1.z, acc.z); acc.w = fmaf(h.y, w1.w, acc.w);
      acc.x = fmaf(h.z, w2.x, acc.x); acc.y = fmaf(h.z, w2.y, acc.y);
      acc.z = fmaf(h.z, w2.z, acc.z); acc.w = fmaf(h.z, w2.w, acc.w);
      acc.x = fmaf(h.w, w3.x, acc.x); acc.y = fmaf(h.w, w3.y, acc.y);
      acc.z = fmaf(h.w, w3.z, acc.z); acc.w = fmaf(h.w, w3.w, acc.w);
    }
    *(float4*)(slot + (tx * 17 + b) * 4) = acc;
  }
  __syncthreads();

  // ================= stage 4: 1 node, waves 0..3 =================
  if (w < 4) {
    const float* P0 = bufA + 0 * SLOTF;
    const float* P1 = bufA + 1 * SLOTF;
    const float* W = weights + (size_t)(3 * NF + T[0]) * (FD * FD);
    const int b = w * 4 + ty;
    float4 acc = make_float4(0.f, 0.f, 0.f, 0.f);
    #pragma unroll 2
    for (int kq = 0; kq < 16; ++kq) {
      const float* Wk = W + kq * 4 * FD + tx * 4;
      float4 w0 = *(const float4*)(Wk);
      float4 w1 = *(const float4*)(Wk + FD);
      float4 w2 = *(const float4*)(Wk + 2 * FD);
      float4 w3 = *(const float4*)(Wk + 3 * FD);
      float4 pa = *(const float4*)(P0 + (kq * 17 + b) * 4);
      float4 pb = *(const float4*)(P1 + (kq * 17 + b) * 4);
      float4 h;
      h.x = pa.x * pb.x; h.y = pa.y * pb.y; h.z = pa.z * pb.z; h.w = pa.w * pb.w;
      acc.x = fmaf(h.x, w0.x, acc.x); acc.y = fmaf(h.x, w0.y, acc.y);
      acc.z = fmaf(h.x, w0.z, acc.z); acc.w = fmaf(h.x, w0.w, acc.w);
      acc.x = fmaf(h.y, w1.x, acc.x); acc.y = fmaf(h.y, w1.y, acc.y);
      acc.z = fmaf(h.y, w1.z, acc.z); acc.w = fmaf(h.y, w1.w, acc.w);
      acc.x = fmaf(h.z, w2.x, acc.x); acc.y = fmaf(h.z, w2.y, acc.y);
      acc.z = fmaf(h.z, w2.z, acc.z); acc.w = fmaf(h.z, w2.w, acc.w);
      acc.x = fmaf(h.w, w3.x, acc.x); acc.y = fmaf(h.w, w3.y, acc.y);
      acc.z = fmaf(h.w, w3.z, acc.z); acc.w = fmaf(h.w, w3.w, acc.w);
    }
    // out[b][o][j], fp32
    *(float4*)(out + ((size_t)(B0 + b) * 8 + o) * FD + tx * 4) = acc;
  }
}

extern "C" void kernel_launch(void* const* d_in, const int* in_sizes, int n_in,
                              void* d_out, int out_size, void* d_ws, size_t ws_size,
                              hipStream_t stream) {
  const float* in_graph = (const float*)d_in[0];
  const float* weights  = (const float*)d_in[1];
  const int*   fold_idx = (const int*)d_in[2];
  const int*   out_idx  = (const int*)d_in[3];
  float* out = (float*)d_out;

  // grid: 8 outputs x 128 batch tiles of 16 rows; d_ws unused.
  fused_dag_kernel<<<(BATCH / BT) * 8, 512, 0, stream>>>(
      in_graph, weights, fold_idx, out_idx, out);
}